// Round 10
// baseline (102.255 us; speedup 1.0000x reference)
//
#include <hip/hip_runtime.h>

// Adaptive Wing loss, reduction='sum', fp32 in/out.
// THETA=0.5, ALPHA=2.1, OMEGA=14.0, EPS=1.0
//   p = 2.1 - target; t = 2^(-p); A = 28*p*t/(1+t)
//   lt (diff<0.5): 14*ln(1+diff^p);  ge: A*(diff-0.5) + 14*ln(1+t)
//
// Ladder: R2 native trans 122->101. R4 strided scatter 120 (revert).
// R5 depth-2 contiguous 97.4 (best). R6 poly+depth4: loads sank, 112.
// R7/R8 sched_barrier pipelines 101.5/102.6 (SIMD lockstep; reverted).
// R9 2x oversubscription: null (98.6) -> revert to 2048 blocks.
// R10: R5 byte-for-byte + fused finish (hipMemsetAsync + one atomicAdd per
//      block) - removes the serial 1-block awl_final dispatch (~3-6us bubble).

#define LN2_X14 9.704060527839234f  // 14 * ln(2)

__device__ __forceinline__ float awl_elem(float x, float tg) {
    float p = 2.1f - tg;
    float t = __builtin_amdgcn_exp2f(-p);                 // 2^(-p)
    float A = 28.0f * p * t * __builtin_amdgcn_rcpf(1.0f + t);
    float diff = fabsf(tg - x);
    // diff^p = 2^(p*log2(diff)); diff==0 -> -inf -> exp2=0 -> log2(1)=0. OK.
    float q = __builtin_amdgcn_exp2f(p * __builtin_amdgcn_logf(diff));
    bool lt = diff < 0.5f;
    float z = lt ? q : t;
    float extra = lt ? 0.0f : A * (diff - 0.5f);
    return fmaf(LN2_X14, __builtin_amdgcn_logf(1.0f + z), extra);
}

__device__ __forceinline__ float awl_quad(float4 a, float4 b) {
    return (awl_elem(a.x, b.x) + awl_elem(a.y, b.y))
         + (awl_elem(a.z, b.z) + awl_elem(a.w, b.w));
}

__global__ __launch_bounds__(256) void awl_sum(
    const float4* __restrict__ x, const float4* __restrict__ tg,
    float* __restrict__ out, int n4)
{
    int tid = blockIdx.x * blockDim.x + threadIdx.x;
    int stride = gridDim.x * blockDim.x;
    int lane = threadIdx.x & 63;
    int wave_base = ((tid >> 6) << 7) + lane;  // wave tiles 128 contiguous float4s
    float acc = 0.0f;

    int s = 0;
    for (; s + 2 * stride <= n4; s += 2 * stride) {
        int i0 = s + wave_base;
        int i1 = i0 + 64;
        float4 a0 = x[i0];
        float4 a1 = x[i1];
        float4 b0 = tg[i0];
        float4 b1 = tg[i1];
        acc += awl_quad(a0, b0);
        acc += awl_quad(a1, b1);
    }
    // generic tail (not hit when n4 % (2*stride) == 0)
    for (int i = s + tid; i < n4; i += stride)
        acc += awl_quad(x[i], tg[i]);

    // wave-64 reduce
    #pragma unroll
    for (int off = 32; off > 0; off >>= 1)
        acc += __shfl_down(acc, off, 64);
    __shared__ float ws[4];
    int wid = threadIdx.x >> 6;
    if (lane == 0) ws[wid] = acc;
    __syncthreads();
    if (threadIdx.x == 0)
        atomicAdd(out, (ws[0] + ws[1]) + (ws[2] + ws[3]));
}

extern "C" void kernel_launch(void* const* d_in, const int* in_sizes, int n_in,
                              void* d_out, int out_size, void* d_ws, size_t ws_size,
                              hipStream_t stream) {
    const float* x  = (const float*)d_in[0];
    const float* tg = (const float*)d_in[1];
    float* out = (float*)d_out;

    long long n = (long long)in_sizes[0];   // 67,108,864 (divisible by 4)
    int n4 = (int)(n / 4);

    int nblk = 2048;                         // resident capacity: 8 blocks/CU

    hipMemsetAsync(out, 0, sizeof(float) * (out_size > 0 ? out_size : 1), stream);
    awl_sum<<<nblk, 256, 0, stream>>>((const float4*)x, (const float4*)tg, out, n4);
}

// Round 11
// 98.587 us; speedup vs baseline: 1.0372x; 1.0372x over previous
//
#include <hip/hip_runtime.h>

// Adaptive Wing loss, reduction='sum', fp32 in/out.
// THETA=0.5, ALPHA=2.1, OMEGA=14.0, EPS=1.0
//   p = 2.1 - target; t = 2^(-p); A = 28*p*t/(1+t)
//   lt (diff<0.5): 14*ln(1+diff^p);  ge: A*(diff-0.5) + 14*ln(1+t)
// Shared-log form: z = diff<0.5 ? diff^p : t;
//   loss = 14*ln(1+z) + (diff<0.5 ? 0 : A*(diff-0.5))
//
// FINAL (champion = R5 structure, 97.4us = 5.5 TB/s effective on 537MB read,
// ~half L3-served). Ladder: R2 native v_exp/v_log/v_rcp 122->101. R4 strided
// scatter 120 (revert). R5 depth-2 contiguous wave-tiled 97.4 (best).
// R6 poly+depth4 loads sank 112. R7/R8 sched_barrier pipelines 101.5/102.6.
// R9 2x oversubscription null. R10 fused atomic finish 102.3 (revert).
// Conclusion: compiler's own schedule at depth-2 contiguous + resident-
// capacity grid is the optimum found; remaining gap to 6.3 TB/s stream
// ceiling is the mixed L3+HBM dual-read service limit, not a fixable stall.

#define LN2_X14 9.704060527839234f  // 14 * ln(2)

__device__ __forceinline__ float awl_elem(float x, float tg) {
    float p = 2.1f - tg;
    float t = __builtin_amdgcn_exp2f(-p);                 // 2^(-p)
    float A = 28.0f * p * t * __builtin_amdgcn_rcpf(1.0f + t);
    float diff = fabsf(tg - x);
    // diff^p = 2^(p*log2(diff)); diff==0 -> -inf -> exp2=0 -> log2(1)=0. OK.
    float q = __builtin_amdgcn_exp2f(p * __builtin_amdgcn_logf(diff));
    bool lt = diff < 0.5f;
    float z = lt ? q : t;
    float extra = lt ? 0.0f : A * (diff - 0.5f);
    return fmaf(LN2_X14, __builtin_amdgcn_logf(1.0f + z), extra);
}

__device__ __forceinline__ float awl_quad(float4 a, float4 b) {
    return (awl_elem(a.x, b.x) + awl_elem(a.y, b.y))
         + (awl_elem(a.z, b.z) + awl_elem(a.w, b.w));
}

__global__ __launch_bounds__(256) void awl_partial(
    const float4* __restrict__ x, const float4* __restrict__ tg,
    float* __restrict__ part, int n4)
{
    int tid = blockIdx.x * blockDim.x + threadIdx.x;
    int stride = gridDim.x * blockDim.x;
    int lane = threadIdx.x & 63;
    int wave_base = ((tid >> 6) << 7) + lane;  // wave tiles 128 contiguous float4s
    float acc = 0.0f;

    int s = 0;
    for (; s + 2 * stride <= n4; s += 2 * stride) {
        int i0 = s + wave_base;
        int i1 = i0 + 64;
        float4 a0 = x[i0];
        float4 a1 = x[i1];
        float4 b0 = tg[i0];
        float4 b1 = tg[i1];
        acc += awl_quad(a0, b0);
        acc += awl_quad(a1, b1);
    }
    // generic tail (not hit when n4 % (2*stride) == 0)
    for (int i = s + tid; i < n4; i += stride)
        acc += awl_quad(x[i], tg[i]);

    // wave-64 reduce
    #pragma unroll
    for (int off = 32; off > 0; off >>= 1)
        acc += __shfl_down(acc, off, 64);
    __shared__ float ws[4];
    int wid = threadIdx.x >> 6;
    if (lane == 0) ws[wid] = acc;
    __syncthreads();
    if (threadIdx.x == 0)
        part[blockIdx.x] = (ws[0] + ws[1]) + (ws[2] + ws[3]);
}

__global__ __launch_bounds__(256) void awl_final(
    const float* __restrict__ part, int n, float* __restrict__ out)
{
    float acc = 0.0f;
    for (int i = threadIdx.x; i < n; i += 256) acc += part[i];
    #pragma unroll
    for (int off = 32; off > 0; off >>= 1)
        acc += __shfl_down(acc, off, 64);
    __shared__ float ws[4];
    int lane = threadIdx.x & 63;
    int wid  = threadIdx.x >> 6;
    if (lane == 0) ws[wid] = acc;
    __syncthreads();
    if (threadIdx.x == 0)
        out[0] = (ws[0] + ws[1]) + (ws[2] + ws[3]);
}

extern "C" void kernel_launch(void* const* d_in, const int* in_sizes, int n_in,
                              void* d_out, int out_size, void* d_ws, size_t ws_size,
                              hipStream_t stream) {
    const float* x  = (const float*)d_in[0];
    const float* tg = (const float*)d_in[1];
    float* out  = (float*)d_out;
    float* part = (float*)d_ws;

    long long n = (long long)in_sizes[0];   // 67,108,864 (divisible by 4)
    int n4 = (int)(n / 4);

    int nblk = 2048;                         // resident capacity: 8 blocks/CU
    int cap = (int)(ws_size / sizeof(float));
    if (cap > 0 && nblk > cap) nblk = cap;
    if (nblk < 1) nblk = 1;

    awl_partial<<<nblk, 256, 0, stream>>>((const float4*)x, (const float4*)tg, part, n4);
    awl_final<<<1, 256, 0, stream>>>(part, nblk, out);
}